// Round 9
// baseline (120.044 us; speedup 1.0000x reference)
//
#include <hip/hip_runtime.h>
#include <math.h>

#define Bb 2
#define Nn 2048
#define Hh 256
#define NH 8
#define NEDGE 65536
#define LN_EPS 1e-5f
#define MW 64          // mask words per row = N/32
#define LDA2 72

typedef __bf16 bf16_t;
typedef bf16_t bf16x8 __attribute__((ext_vector_type(8)));
typedef bf16_t bf16x4 __attribute__((ext_vector_type(4)));
typedef float f32x4 __attribute__((ext_vector_type(4)));

__device__ __forceinline__ bf16x4 cvt4(float4 v) {
    bf16x4 o = {(bf16_t)v.x, (bf16_t)v.y, (bf16_t)v.z, (bf16_t)v.w};
    return o;
}

// ========== K2: edge scatter + QKV MFMA GEMM (inline fp32->bf16 cvt) ========
__global__ __launch_bounds__(256) void qkv_gemm_mask_kernel(
    const float* __restrict__ x,
    const float* __restrict__ Wq, const float* __restrict__ Wk, const float* __restrict__ Wv,
    bf16_t* __restrict__ Qb16, bf16_t* __restrict__ Kb16, bf16_t* __restrict__ Vb16,
    const int* __restrict__ ei, unsigned int* __restrict__ mask)
{
    __shared__ bf16_t As[64 * LDA2];
    __shared__ bf16_t Ws[64 * LDA2];
    int t = threadIdx.x;
    int linb = blockIdx.y * 64 + blockIdx.x;    // 0..767
    int gtid = linb * 256 + t;
    if (gtid < NEDGE) {
        int src = ei[gtid], dst = ei[NEDGE + gtid];
        atomicOr(&mask[src * MW + (dst >> 5)], 1u << (dst & 31));
    }
    int lane = t & 63, w = t >> 6;
    int wm = w & 1, wn = w >> 1;
    int ml = lane & 15, quad = lane >> 4;
    int m0 = blockIdx.x * 64;
    int wsel = blockIdx.y >> 2;
    const float* W = (wsel == 0) ? Wq : ((wsel == 1) ? Wk : Wv);
    int n0 = (blockIdx.y & 3) * 64;
    int srow = t >> 4;            // 0..15
    int scol = (t & 15) * 4;      // 0..60
    f32x4 acc[2][2];
    f32x4 zf = {0.f, 0.f, 0.f, 0.f};
    acc[0][0] = zf; acc[0][1] = zf; acc[1][0] = zf; acc[1][1] = zf;

    for (int k0 = 0; k0 < Hh; k0 += 64) {
        float4 av[4], wv4[4];
        #pragma unroll
        for (int u = 0; u < 4; ++u) {
            av[u]  = *(const float4*)(x + (size_t)(m0 + u * 16 + srow) * Hh + k0 + scol);
            wv4[u] = *(const float4*)(W + (size_t)(n0 + u * 16 + srow) * Hh + k0 + scol);
        }
        __syncthreads();
        #pragma unroll
        for (int u = 0; u < 4; ++u) {
            *(bf16x4*)&As[(u * 16 + srow) * LDA2 + scol] = cvt4(av[u]);
            *(bf16x4*)&Ws[(u * 16 + srow) * LDA2 + scol] = cvt4(wv4[u]);
        }
        __syncthreads();
        #pragma unroll
        for (int kk = 0; kk < 64; kk += 32) {
            bf16x8 af[2], bfr[2];
            #pragma unroll
            for (int i2 = 0; i2 < 2; ++i2) {
                af[i2]  = *(const bf16x8*)&As[(wm * 32 + i2 * 16 + ml) * LDA2 + kk + quad * 8];
                bfr[i2] = *(const bf16x8*)&Ws[(wn * 32 + i2 * 16 + ml) * LDA2 + kk + quad * 8];
            }
            #pragma unroll
            for (int i2 = 0; i2 < 2; ++i2)
                #pragma unroll
                for (int j2 = 0; j2 < 2; ++j2)
                    acc[i2][j2] = __builtin_amdgcn_mfma_f32_16x16x32_bf16(af[i2], bfr[j2], acc[i2][j2], 0, 0, 0);
        }
    }
    bf16_t* Ob16 = (wsel == 0) ? Qb16 : ((wsel == 1) ? Kb16 : Vb16);
    #pragma unroll
    for (int i2 = 0; i2 < 2; ++i2)
        #pragma unroll
        for (int j2 = 0; j2 < 2; ++j2)
            #pragma unroll
            for (int r = 0; r < 4; ++r) {
                int mg = m0 + wm * 32 + i2 * 16 + quad * 4 + r;
                int ng = n0 + wn * 32 + j2 * 16 + ml;
                Ob16[(size_t)mg * Hh + ng] = (bf16_t)acc[i2][j2][r];
            }
}

// ====== K3: sparse attention, 1 row/block. Conflict-free sw[r*9+h] layout,
// double-buffered sw (2 barriers/chunk), clamped unconditional K/V loads. =====
__global__ __launch_bounds__(256) void attn7_kernel(
    const bf16_t* __restrict__ Qb16, const bf16_t* __restrict__ Kb16, const bf16_t* __restrict__ Vb16,
    const unsigned int* __restrict__ mask, float* __restrict__ attnb)
{
    __shared__ unsigned short nbr[Nn];   // 4 KB
    __shared__ float qs[Hh];
    __shared__ float sw[2][32 * 9];      // double-buffered scores/weights [r*9+h]
    __shared__ float alpha_l[NH];
    __shared__ float linv_l[NH];
    __shared__ float obuf[4][Hh];        // 4 KB
    __shared__ int nn_sh;
    int gid = blockIdx.x;                // == b*Nn + i
    int i = gid & (Nn - 1);
    int t = threadIdx.x;
    int h = t >> 5, dl = t & 31;
    int w = t >> 6, lane = t & 63;
    int hw = lane >> 3;                  // head owning cols 4*lane..4*lane+3
    int kvbase = (gid >> 11) << 11;      // b*Nn

    float qreg = (float)Qb16[(size_t)gid * Hh + t];   // issue early
    if (t < 64) {   // wave 0: extract dedup'd neighbor list from bitmask
        unsigned int bits = mask[i * MW + t];
        int cnt = __popc(bits);
        int incl = cnt;
        #pragma unroll
        for (int off = 1; off < 64; off <<= 1) {
            int v = __shfl_up(incl, off, 64);
            if (t >= off) incl += v;
        }
        int idx = incl - cnt;
        unsigned int bb = bits;
        while (bb) {
            int bit = __ffs(bb) - 1;
            nbr[idx++] = (unsigned short)(t * 32 + bit);
            bb &= bb - 1;
        }
        if (t == 63) nn_sh = incl;
    }
    qs[t] = qreg;
    __syncthreads();
    int nn = nn_sh;

    float m_run = -1e30f, l_run = 0.f;
    float o0 = 0.f, o1 = 0.f, o2 = 0.f, o3 = 0.f;
    const float scale = 0.17677669529663687f;  // 1/sqrt(32)
    int nch = (nn + 31) >> 5;
    for (int c = 0; c < nch; ++c) {
        int cb = c & 1;
        int base = c << 5;
        int lim = min(32, nn - base);
        // ---- scores: wave w rows w,w+4,...; lane covers cols 4l..4l+3 ----
        float4 qv = *(const float4*)&qs[lane << 2];
        #pragma unroll
        for (int s = 0; s < 8; ++s) {
            int r = (s << 2) + w;
            int j = nbr[min(base + r, nn - 1)];          // clamped: always valid
            bf16x4 kv = *(const bf16x4*)(Kb16 + (((size_t)(kvbase + j)) << 8) + (lane << 2));
            float p = fmaf((float)kv.x, qv.x, fmaf((float)kv.y, qv.y,
                      fmaf((float)kv.z, qv.z, (float)kv.w * qv.w)));
            p += __shfl_xor(p, 1, 64);
            p += __shfl_xor(p, 2, 64);
            p += __shfl_xor(p, 4, 64);
            if ((lane & 7) == 0 && r < lim) sw[cb][r * 9 + (lane >> 3)] = p * scale;
        }
        __syncthreads();
        // ---- softmax: thread (h,dl) owns its own slot (no intra-phase hazard) ----
        float s_val = (dl < lim) ? sw[cb][dl * 9 + h] : -1e30f;
        float mc = s_val;
        #pragma unroll
        for (int m = 1; m < 32; m <<= 1) mc = fmaxf(mc, __shfl_xor(mc, m, 64));
        float m_new = fmaxf(m_run, mc);
        float wgt = __expf(s_val - m_new);    // 0 for padded lanes
        float sum = wgt;
        #pragma unroll
        for (int m = 1; m < 32; m <<= 1) sum += __shfl_xor(sum, m, 64);
        float alpha = __expf(m_run - m_new);
        l_run = l_run * alpha + sum;
        m_run = m_new;
        sw[cb][dl * 9 + h] = wgt;             // overwrite own slot (all 32 written)
        if (dl == 0) alpha_l[h] = alpha;
        __syncthreads();
        // ---- V accumulate: wave w rows w,w+4,...; thread covers 4 cols ----
        float av = alpha_l[hw];
        o0 *= av; o1 *= av; o2 *= av; o3 *= av;
        #pragma unroll
        for (int s = 0; s < 8; ++s) {
            int r = (s << 2) + w;
            int j = nbr[min(base + r, nn - 1)];
            float wg = sw[cb][r * 9 + hw];    // 0 beyond lim
            bf16x4 vv = *(const bf16x4*)(Vb16 + (((size_t)(kvbase + j)) << 8) + (lane << 2));
            o0 = fmaf(wg, (float)vv.x, o0);
            o1 = fmaf(wg, (float)vv.y, o1);
            o2 = fmaf(wg, (float)vv.z, o2);
            o3 = fmaf(wg, (float)vv.w, o3);
        }
        // no end-of-chunk barrier: next chunk writes sw[cb^1]; alpha_l rewrite
        // is fenced by next chunk's post-score barrier.
    }
    if (dl == 0) linv_l[h] = (l_run > 0.f) ? 1.f / l_run : 0.f;
    float4 ov = {o0, o1, o2, o3};
    *(float4*)&obuf[w][lane << 2] = ov;
    __syncthreads();
    float val = obuf[0][t] + obuf[1][t] + obuf[2][t] + obuf[3][t];
    attnb[((size_t)gid << 8) + t] = val * linv_l[t >> 5];
}

// ====== K4: out = LN(attn @ Wo^T + x), 16 rows/block, inline Wo cvt ========
__global__ __launch_bounds__(256) void out_ln_kernel(
    const float* __restrict__ attnb, const float* __restrict__ Wo,
    const float* __restrict__ x, const float* __restrict__ gamma,
    const float* __restrict__ beta, float* __restrict__ out)
{
    __shared__ bf16_t As[16 * LDA2];
    __shared__ __align__(16) char wbuf[256 * LDA2 * sizeof(bf16_t)];  // 36.9 KB
    bf16_t* Ws = (bf16_t*)wbuf;
    float* yb = (float*)wbuf;          // 16 x 260 fp32, aliased after use
    int t = threadIdx.x;
    int lane = t & 63, w = t >> 6;
    int ml = lane & 15, quad = lane >> 4;
    int m0 = blockIdx.x * 16;
    f32x4 acc[4];
    f32x4 zf = {0.f, 0.f, 0.f, 0.f};
    acc[0] = zf; acc[1] = zf; acc[2] = zf; acc[3] = zf;
    int arow = t >> 4, acol = (t & 15) * 4;
    int wrow = t >> 3, wcol = (t & 7) * 8;

    for (int k0 = 0; k0 < Hh; k0 += 64) {
        float4 av = *(const float4*)(attnb + (size_t)(m0 + arow) * Hh + k0 + acol);
        float4 wa[8], wb[8];
        #pragma unroll
        for (int s = 0; s < 8; ++s) {
            wa[s] = *(const float4*)(Wo + (size_t)(wrow + s * 32) * Hh + k0 + wcol);
            wb[s] = *(const float4*)(Wo + (size_t)(wrow + s * 32) * Hh + k0 + wcol + 4);
        }
        __syncthreads();
        *(bf16x4*)&As[arow * LDA2 + acol] = cvt4(av);
        #pragma unroll
        for (int s = 0; s < 8; ++s) {
            *(bf16x4*)&Ws[(wrow + s * 32) * LDA2 + wcol]     = cvt4(wa[s]);
            *(bf16x4*)&Ws[(wrow + s * 32) * LDA2 + wcol + 4] = cvt4(wb[s]);
        }
        __syncthreads();
        #pragma unroll
        for (int kk = 0; kk < 64; kk += 32) {
            bf16x8 af = *(const bf16x8*)&As[ml * LDA2 + kk + quad * 8];
            #pragma unroll
            for (int ct = 0; ct < 4; ++ct) {
                bf16x8 bfr = *(const bf16x8*)&Ws[(w * 64 + ct * 16 + ml) * LDA2 + kk + quad * 8];
                acc[ct] = __builtin_amdgcn_mfma_f32_16x16x32_bf16(af, bfr, acc[ct], 0, 0, 0);
            }
        }
    }
    __syncthreads();   // all Ws reads done before aliasing as yb
    #pragma unroll
    for (int ct = 0; ct < 4; ++ct)
        #pragma unroll
        for (int r = 0; r < 4; ++r) {
            int row = quad * 4 + r;
            int col = w * 64 + ct * 16 + ml;
            yb[row * 260 + col] = acc[ct][r] + x[(size_t)(m0 + row) * Hh + col];
        }
    __syncthreads();
    for (int rr = 0; rr < 4; ++rr) {
        int row = w * 4 + rr;
        float4 v = *(const float4*)&yb[row * 260 + lane * 4];
        float sum = v.x + v.y + v.z + v.w;
        #pragma unroll
        for (int m = 1; m < 64; m <<= 1) sum += __shfl_xor(sum, m, 64);
        float mu = sum * (1.f / Hh);
        float4 d = {v.x - mu, v.y - mu, v.z - mu, v.w - mu};
        float ss = d.x * d.x + d.y * d.y + d.z * d.z + d.w * d.w;
        #pragma unroll
        for (int m = 1; m < 64; m <<= 1) ss += __shfl_xor(ss, m, 64);
        float r = rsqrtf(ss * (1.f / Hh) + LN_EPS);
        float4 g  = *(const float4*)(gamma + lane * 4);
        float4 bt = *(const float4*)(beta + lane * 4);
        float4 ov = {d.x * r * g.x + bt.x, d.y * r * g.y + bt.y,
                     d.z * r * g.z + bt.z, d.w * r * g.w + bt.w};
        *(float4*)(out + (size_t)(m0 + row) * Hh + lane * 4) = ov;
    }
}

extern "C" void kernel_launch(void* const* d_in, const int* in_sizes, int n_in,
                              void* d_out, int out_size, void* d_ws, size_t ws_size,
                              hipStream_t stream) {
    const float* x     = (const float*)d_in[0];
    const int*   ei    = (const int*)d_in[1];
    // d_in[2] = edge_weights: unused by the reference
    const float* Wq    = (const float*)d_in[3];
    const float* Wk    = (const float*)d_in[4];
    const float* Wv    = (const float*)d_in[5];
    const float* Wo    = (const float*)d_in[6];
    const float* gamma = (const float*)d_in[7];
    const float* beta  = (const float*)d_in[8];
    float* out = (float*)d_out;

    const int NTOK = Bb * Nn * Hh;  // 1048576
    bf16_t* Qb16  = (bf16_t*)d_ws;
    bf16_t* Kb16  = Qb16 + NTOK;
    bf16_t* Vb16  = Kb16 + NTOK;
    float*  attnb = (float*)(Vb16 + NTOK);
    unsigned int* mask = (unsigned int*)(attnb + NTOK);

    hipMemsetAsync(mask, 0, Nn * MW * sizeof(unsigned int), stream);
    hipLaunchKernelGGL(qkv_gemm_mask_kernel, dim3(64, 12), dim3(256), 0, stream,
                       x, Wq, Wk, Wv, Qb16, Kb16, Vb16, ei, mask);
    hipLaunchKernelGGL(attn7_kernel, dim3(Bb * Nn), dim3(256), 0, stream,
                       Qb16, Kb16, Vb16, mask, attnb);
    hipLaunchKernelGGL(out_ln_kernel, dim3((Bb * Nn) / 16), dim3(256), 0, stream,
                       attnb, Wo, x, gamma, beta, out);
}

// Round 10
// 119.838 us; speedup vs baseline: 1.0017x; 1.0017x over previous
//
#include <hip/hip_runtime.h>
#include <math.h>

#define Bb 2
#define Nn 2048
#define Hh 256
#define NH 8
#define NEDGE 65536
#define LN_EPS 1e-5f
#define MW 64          // mask words per row = N/32
#define LDA2 72

typedef __bf16 bf16_t;
typedef bf16_t bf16x8 __attribute__((ext_vector_type(8)));
typedef bf16_t bf16x4 __attribute__((ext_vector_type(4)));
typedef float f32x4 __attribute__((ext_vector_type(4)));

__device__ __forceinline__ bf16x4 cvt4(float4 v) {
    bf16x4 o = {(bf16_t)v.x, (bf16_t)v.y, (bf16_t)v.z, (bf16_t)v.w};
    return o;
}

// ========== K2: edge scatter + QKV MFMA GEMM (inline fp32->bf16 cvt) ========
__global__ __launch_bounds__(256) void qkv_gemm_mask_kernel(
    const float* __restrict__ x,
    const float* __restrict__ Wq, const float* __restrict__ Wk, const float* __restrict__ Wv,
    float* __restrict__ Qb, bf16_t* __restrict__ Kb16, bf16_t* __restrict__ Vb16,
    const int* __restrict__ ei, unsigned int* __restrict__ mask)
{
    __shared__ bf16_t As[64 * LDA2];
    __shared__ bf16_t Ws[64 * LDA2];
    int t = threadIdx.x;
    int linb = blockIdx.y * 64 + blockIdx.x;    // 0..767
    int gtid = linb * 256 + t;
    if (gtid < NEDGE) {
        int src = ei[gtid], dst = ei[NEDGE + gtid];
        atomicOr(&mask[src * MW + (dst >> 5)], 1u << (dst & 31));
    }
    int lane = t & 63, w = t >> 6;
    int wm = w & 1, wn = w >> 1;
    int ml = lane & 15, quad = lane >> 4;
    int m0 = blockIdx.x * 64;
    int wsel = blockIdx.y >> 2;
    const float* W = (wsel == 0) ? Wq : ((wsel == 1) ? Wk : Wv);
    int n0 = (blockIdx.y & 3) * 64;
    int srow = t >> 4;            // 0..15
    int scol = (t & 15) * 4;      // 0..60
    f32x4 acc[2][2];
    f32x4 zf = {0.f, 0.f, 0.f, 0.f};
    acc[0][0] = zf; acc[0][1] = zf; acc[1][0] = zf; acc[1][1] = zf;

    for (int k0 = 0; k0 < Hh; k0 += 64) {
        float4 av[4], wv4[4];
        #pragma unroll
        for (int u = 0; u < 4; ++u) {
            av[u]  = *(const float4*)(x + (size_t)(m0 + u * 16 + srow) * Hh + k0 + scol);
            wv4[u] = *(const float4*)(W + (size_t)(n0 + u * 16 + srow) * Hh + k0 + scol);
        }
        __syncthreads();
        #pragma unroll
        for (int u = 0; u < 4; ++u) {
            *(bf16x4*)&As[(u * 16 + srow) * LDA2 + scol] = cvt4(av[u]);
            *(bf16x4*)&Ws[(u * 16 + srow) * LDA2 + scol] = cvt4(wv4[u]);
        }
        __syncthreads();
        #pragma unroll
        for (int kk = 0; kk < 64; kk += 32) {
            bf16x8 af[2], bfr[2];
            #pragma unroll
            for (int i2 = 0; i2 < 2; ++i2) {
                af[i2]  = *(const bf16x8*)&As[(wm * 32 + i2 * 16 + ml) * LDA2 + kk + quad * 8];
                bfr[i2] = *(const bf16x8*)&Ws[(wn * 32 + i2 * 16 + ml) * LDA2 + kk + quad * 8];
            }
            #pragma unroll
            for (int i2 = 0; i2 < 2; ++i2)
                #pragma unroll
                for (int j2 = 0; j2 < 2; ++j2)
                    acc[i2][j2] = __builtin_amdgcn_mfma_f32_16x16x32_bf16(af[i2], bfr[j2], acc[i2][j2], 0, 0, 0);
        }
    }
    #pragma unroll
    for (int i2 = 0; i2 < 2; ++i2)
        #pragma unroll
        for (int j2 = 0; j2 < 2; ++j2)
            #pragma unroll
            for (int r = 0; r < 4; ++r) {
                int mg = m0 + wm * 32 + i2 * 16 + quad * 4 + r;
                int ng = n0 + wn * 32 + j2 * 16 + ml;
                float v = acc[i2][j2][r];
                if (wsel == 0)      Qb[(size_t)mg * Hh + ng] = v;
                else if (wsel == 1) Kb16[(size_t)mg * Hh + ng] = (bf16_t)v;
                else                Vb16[(size_t)mg * Hh + ng] = (bf16_t)v;
            }
}

// ====== K3: sparse attention, 1 row/block. Conflict-free sw[r*9+h] layout,
// double-buffered sw (2 barriers/chunk), clamped unconditional K/V loads,
// bf16 output. ======
__global__ __launch_bounds__(256) void attn8_kernel(
    const float* __restrict__ Qb, const bf16_t* __restrict__ Kb16, const bf16_t* __restrict__ Vb16,
    const unsigned int* __restrict__ mask, bf16_t* __restrict__ attnb16)
{
    __shared__ unsigned short nbr[Nn];   // 4 KB
    __shared__ float qs[Hh];
    __shared__ float sw[2][32 * 9];      // double-buffered scores/weights [r*9+h]
    __shared__ float alpha_l[NH];
    __shared__ float linv_l[NH];
    __shared__ float obuf[4][Hh];        // 4 KB
    __shared__ int nn_sh;
    int gid = blockIdx.x;                // == b*Nn + i
    int i = gid & (Nn - 1);
    int t = threadIdx.x;
    int h = t >> 5, dl = t & 31;
    int w = t >> 6, lane = t & 63;
    int hw = lane >> 3;                  // head owning cols 4*lane..4*lane+3
    int kvbase = (gid >> 11) << 11;      // b*Nn

    float qreg = Qb[(size_t)gid * Hh + t];   // issue early
    if (t < 64) {   // wave 0: extract dedup'd neighbor list from bitmask
        unsigned int bits = mask[i * MW + t];
        int cnt = __popc(bits);
        int incl = cnt;
        #pragma unroll
        for (int off = 1; off < 64; off <<= 1) {
            int v = __shfl_up(incl, off, 64);
            if (t >= off) incl += v;
        }
        int idx = incl - cnt;
        unsigned int bb = bits;
        while (bb) {
            int bit = __ffs(bb) - 1;
            nbr[idx++] = (unsigned short)(t * 32 + bit);
            bb &= bb - 1;
        }
        if (t == 63) nn_sh = incl;
    }
    qs[t] = qreg;
    __syncthreads();
    int nn = nn_sh;

    float m_run = -1e30f, l_run = 0.f;
    float o0 = 0.f, o1 = 0.f, o2 = 0.f, o3 = 0.f;
    const float scale = 0.17677669529663687f;  // 1/sqrt(32)
    int nch = (nn + 31) >> 5;
    for (int c = 0; c < nch; ++c) {
        int cb = c & 1;
        int base = c << 5;
        int lim = min(32, nn - base);
        // ---- scores: wave w rows w,w+4,...; lane covers cols 4l..4l+3 ----
        float4 qv = *(const float4*)&qs[lane << 2];
        #pragma unroll
        for (int s = 0; s < 8; ++s) {
            int r = (s << 2) + w;
            int j = nbr[min(base + r, nn - 1)];          // clamped: always valid
            bf16x4 kv = *(const bf16x4*)(Kb16 + (((size_t)(kvbase + j)) << 8) + (lane << 2));
            float p = fmaf((float)kv.x, qv.x, fmaf((float)kv.y, qv.y,
                      fmaf((float)kv.z, qv.z, (float)kv.w * qv.w)));
            p += __shfl_xor(p, 1, 64);
            p += __shfl_xor(p, 2, 64);
            p += __shfl_xor(p, 4, 64);
            if ((lane & 7) == 0 && r < lim) sw[cb][r * 9 + (lane >> 3)] = p * scale;
        }
        __syncthreads();
        // ---- softmax: thread (h,dl) owns its own slot ----
        float s_val = (dl < lim) ? sw[cb][dl * 9 + h] : -1e30f;
        float mc = s_val;
        #pragma unroll
        for (int m = 1; m < 32; m <<= 1) mc = fmaxf(mc, __shfl_xor(mc, m, 64));
        float m_new = fmaxf(m_run, mc);
        float wgt = __expf(s_val - m_new);    // 0 for padded lanes
        float sum = wgt;
        #pragma unroll
        for (int m = 1; m < 32; m <<= 1) sum += __shfl_xor(sum, m, 64);
        float alpha = __expf(m_run - m_new);
        l_run = l_run * alpha + sum;
        m_run = m_new;
        sw[cb][dl * 9 + h] = wgt;             // overwrite own slot (all 32 written)
        if (dl == 0) alpha_l[h] = alpha;
        __syncthreads();
        // ---- V accumulate: wave w rows w,w+4,...; thread covers 4 cols ----
        float av = alpha_l[hw];
        o0 *= av; o1 *= av; o2 *= av; o3 *= av;
        #pragma unroll
        for (int s = 0; s < 8; ++s) {
            int r = (s << 2) + w;
            int j = nbr[min(base + r, nn - 1)];
            float wg = sw[cb][r * 9 + hw];    // 0 beyond lim
            bf16x4 vv = *(const bf16x4*)(Vb16 + (((size_t)(kvbase + j)) << 8) + (lane << 2));
            o0 = fmaf(wg, (float)vv.x, o0);
            o1 = fmaf(wg, (float)vv.y, o1);
            o2 = fmaf(wg, (float)vv.z, o2);
            o3 = fmaf(wg, (float)vv.w, o3);
        }
        // no end-of-chunk barrier: next chunk writes sw[cb^1]; alpha_l rewrite
        // is fenced behind next chunk's post-score barrier.
    }
    if (dl == 0) linv_l[h] = (l_run > 0.f) ? 1.f / l_run : 0.f;
    float4 ov = {o0, o1, o2, o3};
    *(float4*)&obuf[w][lane << 2] = ov;
    __syncthreads();
    float val = obuf[0][t] + obuf[1][t] + obuf[2][t] + obuf[3][t];
    attnb16[((size_t)gid << 8) + t] = (bf16_t)(val * linv_l[t >> 5]);
}

// ====== K4: out = LN(attn @ Wo^T + x), 16 rows/block, bf16 attn in ========
__global__ __launch_bounds__(256) void out_ln_kernel(
    const bf16_t* __restrict__ attnb16, const float* __restrict__ Wo,
    const float* __restrict__ x, const float* __restrict__ gamma,
    const float* __restrict__ beta, float* __restrict__ out)
{
    __shared__ bf16_t As[16 * LDA2];
    __shared__ __align__(16) char wbuf[256 * LDA2 * sizeof(bf16_t)];  // 36.9 KB
    bf16_t* Ws = (bf16_t*)wbuf;
    float* yb = (float*)wbuf;          // 16 x 260 fp32, aliased after use
    int t = threadIdx.x;
    int lane = t & 63, w = t >> 6;
    int ml = lane & 15, quad = lane >> 4;
    int m0 = blockIdx.x * 16;
    f32x4 acc[4];
    f32x4 zf = {0.f, 0.f, 0.f, 0.f};
    acc[0] = zf; acc[1] = zf; acc[2] = zf; acc[3] = zf;
    int arow = t >> 4, acol = (t & 15) * 4;
    int wrow = t >> 3, wcol = (t & 7) * 8;

    for (int k0 = 0; k0 < Hh; k0 += 64) {
        bf16x4 av = *(const bf16x4*)(attnb16 + (size_t)(m0 + arow) * Hh + k0 + acol);
        float4 wa[8], wb[8];
        #pragma unroll
        for (int s = 0; s < 8; ++s) {
            wa[s] = *(const float4*)(Wo + (size_t)(wrow + s * 32) * Hh + k0 + wcol);
            wb[s] = *(const float4*)(Wo + (size_t)(wrow + s * 32) * Hh + k0 + wcol + 4);
        }
        __syncthreads();
        *(bf16x4*)&As[arow * LDA2 + acol] = av;
        #pragma unroll
        for (int s = 0; s < 8; ++s) {
            *(bf16x4*)&Ws[(wrow + s * 32) * LDA2 + wcol]     = cvt4(wa[s]);
            *(bf16x4*)&Ws[(wrow + s * 32) * LDA2 + wcol + 4] = cvt4(wb[s]);
        }
        __syncthreads();
        #pragma unroll
        for (int kk = 0; kk < 64; kk += 32) {
            bf16x8 af = *(const bf16x8*)&As[ml * LDA2 + kk + quad * 8];
            #pragma unroll
            for (int ct = 0; ct < 4; ++ct) {
                bf16x8 bfr = *(const bf16x8*)&Ws[(w * 64 + ct * 16 + ml) * LDA2 + kk + quad * 8];
                acc[ct] = __builtin_amdgcn_mfma_f32_16x16x32_bf16(af, bfr, acc[ct], 0, 0, 0);
            }
        }
    }
    __syncthreads();   // all Ws reads done before aliasing as yb
    #pragma unroll
    for (int ct = 0; ct < 4; ++ct)
        #pragma unroll
        for (int r = 0; r < 4; ++r) {
            int row = quad * 4 + r;
            int col = w * 64 + ct * 16 + ml;
            yb[row * 260 + col] = acc[ct][r] + x[(size_t)(m0 + row) * Hh + col];
        }
    __syncthreads();
    for (int rr = 0; rr < 4; ++rr) {
        int row = w * 4 + rr;
        float4 v = *(const float4*)&yb[row * 260 + lane * 4];
        float sum = v.x + v.y + v.z + v.w;
        #pragma unroll
        for (int m = 1; m < 64; m <<= 1) sum += __shfl_xor(sum, m, 64);
        float mu = sum * (1.f / Hh);
        float4 d = {v.x - mu, v.y - mu, v.z - mu, v.w - mu};
        float ss = d.x * d.x + d.y * d.y + d.z * d.z + d.w * d.w;
        #pragma unroll
        for (int m = 1; m < 64; m <<= 1) ss += __shfl_xor(ss, m, 64);
        float r = rsqrtf(ss * (1.f / Hh) + LN_EPS);
        float4 g  = *(const float4*)(gamma + lane * 4);
        float4 bt = *(const float4*)(beta + lane * 4);
        float4 ov = {d.x * r * g.x + bt.x, d.y * r * g.y + bt.y,
                     d.z * r * g.z + bt.z, d.w * r * g.w + bt.w};
        *(float4*)(out + (size_t)(m0 + row) * Hh + lane * 4) = ov;
    }
}

extern "C" void kernel_launch(void* const* d_in, const int* in_sizes, int n_in,
                              void* d_out, int out_size, void* d_ws, size_t ws_size,
                              hipStream_t stream) {
    const float* x     = (const float*)d_in[0];
    const int*   ei    = (const int*)d_in[1];
    // d_in[2] = edge_weights: unused by the reference
    const float* Wq    = (const float*)d_in[3];
    const float* Wk    = (const float*)d_in[4];
    const float* Wv    = (const float*)d_in[5];
    const float* Wo    = (const float*)d_in[6];
    const float* gamma = (const float*)d_in[7];
    const float* beta  = (const float*)d_in[8];
    float* out = (float*)d_out;

    const int NTOK = Bb * Nn * Hh;  // 1048576
    float*  Qb      = (float*)d_ws;
    bf16_t* Kb16    = (bf16_t*)(Qb + NTOK);
    bf16_t* Vb16    = Kb16 + NTOK;
    bf16_t* attnb16 = Vb16 + NTOK;
    unsigned int* mask = (unsigned int*)(attnb16 + NTOK);

    hipMemsetAsync(mask, 0, Nn * MW * sizeof(unsigned int), stream);
    hipLaunchKernelGGL(qkv_gemm_mask_kernel, dim3(64, 12), dim3(256), 0, stream,
                       x, Wq, Wk, Wv, Qb, Kb16, Vb16, ei, mask);
    hipLaunchKernelGGL(attn8_kernel, dim3(Bb * Nn), dim3(256), 0, stream,
                       Qb, Kb16, Vb16, mask, attnb16);
    hipLaunchKernelGGL(out_ln_kernel, dim3((Bb * Nn) / 16), dim3(256), 0, stream,
                       attnb16, Wo, x, gamma, beta, out);
}